// Round 3
// baseline (182.921 us; speedup 1.0000x reference)
//
#include <hip/hip_runtime.h>

typedef __bf16 bf16;
typedef __bf16 bf16x4 __attribute__((ext_vector_type(4)));
typedef __bf16 bf16x8 __attribute__((ext_vector_type(8)));
typedef float f32x4 __attribute__((ext_vector_type(4)));

#define MFMA16(a, b, c) __builtin_amdgcn_mfma_f32_16x16x32_bf16((a), (b), (c), 0, 0, 0)

// B=256, T=320, C=1024, H=64.  One block per batch, 4 waves.
// LDS (bytes): K @0 [t:320][128B] swz | V @40960 [h:64][640B] swz |
//              Q @81920 [t:320][128B] swz | U @122880 (x-stage [2][64][144B] / P [w:4][16][640B] swz)
#define OFFK 0
#define OFFV 40960
#define OFFQ 81920
#define OFFU 122880

// ---------------- Kernel 0: W -> Wt (bf16, [mat][h][k]) ----------------
__global__ __launch_bounds__(256) void wtrans_kernel(
    const float* __restrict__ Wk, const float* __restrict__ Wq,
    const float* __restrict__ Wv, bf16* __restrict__ Wt) {
  __shared__ bf16 tile[64][65];
  const int mat = blockIdx.x >> 4;
  const int kt = (blockIdx.x & 15) << 6;
  const float* __restrict__ W = (mat == 0) ? Wk : ((mat == 1) ? Wq : Wv);
  const int tid = threadIdx.x;
#pragma unroll
  for (int j = 0; j < 16; ++j) {
    const int i = tid + 256 * j;
    const int k = i >> 6, h = i & 63;
    tile[h][k] = (bf16)W[(kt + k) * 64 + h];
  }
  __syncthreads();
#pragma unroll
  for (int j = 0; j < 16; ++j) {
    const int i = tid + 256 * j;
    const int h = i >> 6, k = i & 63;
    Wt[mat * 65536 + h * 1024 + kt + k] = tile[h][k];
  }
}

// ---------------- Kernel 1: fused QKV projection + causal attention ----------------
__global__ __launch_bounds__(256, 1) void fused_kernel(
    const float* __restrict__ x, const bf16* __restrict__ Wt, float* __restrict__ out) {
  extern __shared__ char smem[];
  const int tid = threadIdx.x;
  const int w = tid >> 6, l = tid & 63, lr = l & 15, lg = l >> 4;
  const int b = blockIdx.x;
  const float* __restrict__ xb = x + (size_t)b * 320 * 1024;

  // ======== phase 1: QKV projection into LDS ========
  f32x4 acc[4][3];
  float4 gA[4], gB[4];
  bf16x8 wf[3][2], wn[3][2];

  auto loadx = [&](int s, float4* gg) {
    const int base = (s >> 4) * 64;
    const int kt = (s & 15) << 6;
#pragma unroll
    for (int j = 0; j < 4; ++j) {
      const int u = tid + 256 * j;
      gg[j] = *(const float4*)(xb + (size_t)(base + (u >> 4)) * 1024 + kt + (u & 15) * 4);
    }
  };
  auto loadw = [&](int kt, bf16x8 wfr[3][2]) {
#pragma unroll
    for (int nf = 0; nf < 3; ++nf) {
      const int colg = w * 48 + nf * 16 + lr;  // 16-col frag never straddles a matrix
      const bf16* p = Wt + (colg >> 6) * 65536 + (colg & 63) * 1024 + kt + lg * 8;
      wfr[nf][0] = *(const bf16x8*)p;
      wfr[nf][1] = *(const bf16x8*)(p + 32);
    }
  };

  loadx(0, gA);
  loadx(1, gB);
  loadw(0, wf);

  auto dostep = [&](int s, float4* gg) {
    if ((s & 15) == 0) {
#pragma unroll
      for (int mf = 0; mf < 4; ++mf)
#pragma unroll
        for (int nf = 0; nf < 3; ++nf) acc[mf][nf] = (f32x4)0.0f;
    }
    const int buf = s & 1;
    char* xsb = smem + OFFU + buf * 9216;
#pragma unroll
    for (int j = 0; j < 4; ++j) {  // fp32 regs -> bf16 LDS
      const int u = tid + 256 * j;
      bf16x4 h4;
      h4[0] = (bf16)gg[j].x; h4[1] = (bf16)gg[j].y;
      h4[2] = (bf16)gg[j].z; h4[3] = (bf16)gg[j].w;
      *(bf16x4*)(xsb + (u >> 4) * 144 + (u & 15) * 8) = h4;
    }
    if (s + 2 < 80) loadx(s + 2, gg);  // depth-2: stays in flight across 2 barriers
    asm volatile("s_waitcnt lgkmcnt(0)" ::: "memory");
    __builtin_amdgcn_sched_barrier(0);
    __builtin_amdgcn_s_barrier();  // raw barrier: vmcnt NOT drained
    __builtin_amdgcn_sched_barrier(0);
    if (s + 1 < 80) loadw(((s + 1) & 15) << 6, wn);
#pragma unroll
    for (int mf = 0; mf < 4; ++mf) {
      const bf16x8 a0 = *(const bf16x8*)(xsb + (mf * 16 + lr) * 144 + lg * 16);
      const bf16x8 a1 = *(const bf16x8*)(xsb + (mf * 16 + lr) * 144 + 64 + lg * 16);
#pragma unroll
      for (int nf = 0; nf < 3; ++nf) {
        acc[mf][nf] = MFMA16(a0, wf[nf][0], acc[mf][nf]);
        acc[mf][nf] = MFMA16(a1, wf[nf][1], acc[mf][nf]);
      }
    }
    if (s + 1 < 80) {
#pragma unroll
      for (int nf = 0; nf < 3; ++nf) { wf[nf][0] = wn[nf][0]; wf[nf][1] = wn[nf][1]; }
    }
    if ((s & 15) == 15) {  // m-tile epilogue: C-frags -> swizzled LDS
      const int mrow0 = (s >> 4) * 64;
#pragma unroll
      for (int mf = 0; mf < 4; ++mf)
#pragma unroll
        for (int nf = 0; nf < 3; ++nf) {
          const int colg = w * 48 + nf * 16 + lr;
          const int mat = colg >> 6, h = colg & 63;  // mat uniform per frag
          const int tl = mrow0 + mf * 16 + lg * 4;
          if (mat == 2) {  // V[h][t]: 4 consecutive t, 8B aligned, within 16B swz unit
            bf16x4 o;
#pragma unroll
            for (int r = 0; r < 4; ++r) o[r] = (bf16)acc[mf][nf][r];
            *(bf16x4*)(smem + OFFV + ((h * 640 + tl * 2) ^ ((h & 7) << 4))) = o;
          } else {
            char* bb = smem + (mat == 0 ? OFFK : OFFQ);
#pragma unroll
            for (int r = 0; r < 4; ++r)
              *(bf16*)(bb + (((tl + r) * 128 + h * 2) ^ (((tl + r) & 7) << 4))) =
                  (bf16)acc[mf][nf][r];
          }
        }
    }
  };

#pragma unroll 1
  for (int sp = 0; sp < 80; sp += 2) {
    dostep(sp, gA);
    dostep(sp + 1, gB);
  }

  __syncthreads();  // full drain; K/Q/V visible to all waves

  // ======== phase 2: causal attention (barrier-free, per-wave) ========
  char* Kb = smem + OFFK;
  char* Qb = smem + OFFQ;
  char* Vb = smem + OFFV;
  char* Pw = smem + OFFU + w * 10240;  // wave-private P [16][640B] swz

#pragma unroll 1
  for (int j = 0; j < 5; ++j) {
    const int qi = w + 4 * j;  // qtile 0..19
    const int t0 = qi * 16;
    const int nfmax = qi + 1;  // live 16-wide s-fragments (causal)
    const int tq = t0 + lr;

    // Q B-fragments (swapped QK^T: lane's q-row = lane&15)
    const bf16x8 bq0 = *(const bf16x8*)(Qb + ((tq * 128 + lg * 16) ^ ((tq & 7) << 4)));
    const bf16x8 bq1 = *(const bf16x8*)(Qb + ((tq * 128 + 64 + lg * 16) ^ ((tq & 7) << 4)));

    f32x4 acs[20];
#pragma unroll
    for (int nf = 0; nf < 20; ++nf) {
      if (nf >= nfmax) break;
      const int sr = nf * 16 + lr;
      const bf16x8 a0 = *(const bf16x8*)(Kb + ((sr * 128 + lg * 16) ^ ((sr & 7) << 4)));
      const bf16x8 a1 = *(const bf16x8*)(Kb + ((sr * 128 + 64 + lg * 16) ^ ((sr & 7) << 4)));
      f32x4 a = (f32x4)0.0f;
      a = MFMA16(a0, bq0, a);
      a = MFMA16(a1, bq1, a);
      acs[nf] = a;
    }

    // scale 1/32, causal mask, softmax over s (lane-local + 2 shuffles)
    float mx = -1e30f;
#pragma unroll
    for (int nf = 0; nf < 20; ++nf) {
      if (nf >= nfmax) break;
#pragma unroll
      for (int r = 0; r < 4; ++r) {
        const int sg = nf * 16 + lg * 4 + r;
        float v = acs[nf][r] * 0.03125f;
        v = (sg > tq) ? -1e30f : v;
        acs[nf][r] = v;
        mx = fmaxf(mx, v);
      }
    }
    mx = fmaxf(mx, __shfl_xor(mx, 16));
    mx = fmaxf(mx, __shfl_xor(mx, 32));
    float sum = 0.f;
#pragma unroll
    for (int nf = 0; nf < 20; ++nf) {
      if (nf >= nfmax) break;
#pragma unroll
      for (int r = 0; r < 4; ++r) {
        const float p = __expf(acs[nf][r] - mx);
        acs[nf][r] = p;
        sum += p;
      }
    }
    sum += __shfl_xor(sum, 16);
    sum += __shfl_xor(sum, 32);
    const float rinv = 1.0f / sum;

    // normalized P -> wave-private swizzled LDS (b64 packed)
#pragma unroll
    for (int nf = 0; nf < 20; ++nf) {
      if (nf >= nfmax) break;
      bf16x4 o;
#pragma unroll
      for (int r = 0; r < 4; ++r) o[r] = (bf16)(acs[nf][r] * rinv);
      *(bf16x4*)(Pw + ((lr * 640 + nf * 32 + lg * 8) ^ ((lr & 7) << 4))) = o;
    }
    if (nfmax & 1) {  // zero the odd 16-col tail so last 32-wide PV step is clean
      bf16x4 z;
      z[0] = z[1] = z[2] = z[3] = (bf16)0.0f;
      *(bf16x4*)(Pw + ((lr * 640 + nfmax * 32 + lg * 8) ^ ((lr & 7) << 4))) = z;
    }

    // O = P V
    const int ksmax = (nfmax + 1) >> 1;
    f32x4 ao[4];
#pragma unroll
    for (int hf = 0; hf < 4; ++hf) ao[hf] = (f32x4)0.0f;
#pragma unroll
    for (int ks = 0; ks < 10; ++ks) {
      if (ks >= ksmax) break;
      const bf16x8 ap = *(const bf16x8*)(Pw + ((lr * 640 + ks * 64 + lg * 16) ^ ((lr & 7) << 4)));
#pragma unroll
      for (int hf = 0; hf < 4; ++hf) {
        const int vh = hf * 16 + lr;
        const bf16x8 bv =
            *(const bf16x8*)(Vb + ((vh * 640 + ks * 64 + lg * 16) ^ ((vh & 7) << 4)));
        ao[hf] = MFMA16(ap, bv, ao[hf]);
      }
    }

    const int rowb = t0 + lg * 4;
#pragma unroll
    for (int hf = 0; hf < 4; ++hf)
#pragma unroll
      for (int r = 0; r < 4; ++r)
        out[((size_t)b * 320 + rowb + r) * 64 + hf * 16 + lr] = ao[hf][r];
  }
}

extern "C" void kernel_launch(void* const* d_in, const int* in_sizes, int n_in,
                              void* d_out, int out_size, void* d_ws, size_t ws_size,
                              hipStream_t stream) {
  const float* x  = (const float*)d_in[0];
  const float* Wk = (const float*)d_in[1];
  const float* Wq = (const float*)d_in[2];
  const float* Wv = (const float*)d_in[3];
  float* out = (float*)d_out;

  bf16* Wt = (bf16*)d_ws;  // [3][64][1024]

  (void)hipFuncSetAttribute((const void*)fused_kernel,
                            hipFuncAttributeMaxDynamicSharedMemorySize, 163840);

  hipLaunchKernelGGL(wtrans_kernel, dim3(48), dim3(256), 0, stream, Wk, Wq, Wv, Wt);
  hipLaunchKernelGGL(fused_kernel, dim3(256), dim3(256), 163840, stream, x, Wt, out);
}